// Round 9
// baseline (56.735 us; speedup 1.0000x reference)
//
#include <hip/hip_runtime.h>

// similarity[r] = sum_a (pp[r,a] - ph[a])^2, a in [0,32); output = min_r similarity[r]
// pp: [R, 32] fp32 row-major, ph: [32] fp32, out: 1 fp32 scalar.
//
// Round-9: round-4 structure exactly (padded-LDS transpose stage + plain-store
// partials + 1024-thread reducer), with ONE change: stage grid = 1024 blocks,
// each grid-striding over 4 tiles of 256 rows with a per-thread running min.
//  - Same occupancy as r4 (4 blocks/CU, 36 KB LDS), same memory pattern.
//  - Partials: 3907 -> 1024, so the reducer does 1 load generation, not 4.
//  - r8's swizzle/slim-reducer/aliasing changes reverted (r8 = +1.9 us).

__global__ __launch_bounds__(256) void doa_stage_kernel(
    const float* __restrict__ pp,
    const float* __restrict__ ph,
    float* __restrict__ ws,
    int R,
    int ntiles)
{
    __shared__ float4 lds[256 * 9];   // 36 KB: 256 rows x (8 data + 1 pad) float4

    const int t = threadIdx.x;

    // phases: wave-uniform -> SGPRs
    float q[32];
#pragma unroll
    for (int a = 0; a < 32; ++a) q[a] = ph[a];

    const float4* src = reinterpret_cast<const float4*>(pp);
    const long long gmax = (long long)R * 8;

    float lmin = __builtin_inff();

    for (int tile = blockIdx.x; tile < ntiles; tile += gridDim.x) {
        const long long base_row = (long long)tile * 256;

        // Stage 1: 8 independent coalesced float4 loads (8 KB/wave in flight).
        // Issued before the barrier so their latency overlaps the wait.
        float4 v[8];
#pragma unroll
        for (int i = 0; i < 8; ++i) {
            long long g = base_row * 8 + i * 256 + t;
            if (g >= gmax) g = 0;          // clamp; value unused for r >= R
            v[i] = src[g];
        }

        __syncthreads();   // previous tile's LDS reads complete before overwrite
#pragma unroll
        for (int i = 0; i < 8; ++i) {
            const int idx = i * 256 + t;   // float4 index within tile's 256 rows
            lds[(idx >> 3) * 9 + (idx & 7)] = v[i];   // padded stride: conflict-free
        }
        __syncthreads();

        // Stage 2: each lane computes its own row from LDS, running min in reg.
        if (base_row + t < R) {
            float s = 0.0f;
#pragma unroll
            for (int k = 0; k < 8; ++k) {
                const float4 p = lds[t * 9 + k];
                const float dx = p.x - q[4 * k + 0];
                const float dy = p.y - q[4 * k + 1];
                const float dz = p.z - q[4 * k + 2];
                const float dw = p.w - q[4 * k + 3];
                s += dx * dx + dy * dy + dz * dz + dw * dw;
            }
            lmin = fminf(lmin, s);
        }
    }

    // one wave-wide min butterfly per block lifetime
#pragma unroll
    for (int off = 1; off < 64; off <<= 1)
        lmin = fminf(lmin, __shfl_xor(lmin, off));

    __shared__ float wmin[4];
    if ((t & 63) == 0) wmin[t >> 6] = lmin;
    __syncthreads();
    if (t == 0) {
        // plain store: fire-and-forget, no atomic tail
        ws[blockIdx.x] = fminf(fminf(wmin[0], wmin[1]), fminf(wmin[2], wmin[3]));
    }
}

__global__ __launch_bounds__(1024) void doa_reduce_kernel(
    const float* __restrict__ ws,
    float* __restrict__ out,
    int n)
{
    float s = __builtin_inff();
    for (int i = threadIdx.x; i < n; i += 1024)
        s = fminf(s, ws[i]);

#pragma unroll
    for (int off = 1; off < 64; off <<= 1)
        s = fminf(s, __shfl_xor(s, off));

    __shared__ float wmin[16];
    if ((threadIdx.x & 63) == 0) wmin[threadIdx.x >> 6] = s;
    __syncthreads();
    if (threadIdx.x == 0) {
        float m = wmin[0];
#pragma unroll
        for (int w = 1; w < 16; ++w) m = fminf(m, wmin[w]);
        *out = m;
    }
}

extern "C" void kernel_launch(void* const* d_in, const int* in_sizes, int n_in,
                              void* d_out, int out_size, void* d_ws, size_t ws_size,
                              hipStream_t stream) {
    const float* pp = (const float*)d_in[0];   // possible_phases [R, 32]
    const float* ph = (const float*)d_in[1];   // phases [32]
    float* out = (float*)d_out;                // 1 fp32 scalar
    float* ws  = (float*)d_ws;                 // per-block partial mins

    const int R = in_sizes[0] / 32;
    const int ntiles = (R + 255) / 256;        // 3907 tiles for R = 1e6
    const int grid = 1024;                     // all co-resident (4 blocks/CU)

    doa_stage_kernel<<<grid, 256, 0, stream>>>(pp, ph, ws, R, ntiles);
    doa_reduce_kernel<<<1, 1024, 0, stream>>>(ws, out, grid);
}

// Round 10
// 25.582 us; speedup vs baseline: 2.2178x; 2.2178x over previous
//
#include <hip/hip_runtime.h>

// similarity[r] = sum_a (pp[r,a] - ph[a])^2, a in [0,32); output = min_r similarity[r]
// pp: [R, 32] fp32 row-major, ph: [32] fp32, out: 1 fp32 scalar.
//
// Round-10: r4's two-node structure, but the stage drops the LDS transpose.
// Key identity: with coalesced float4 index g = blk*2048 + i*256 + t, the
// chunk id (g & 7) == (t & 7) for ALL i (256 = 0 mod 8). Each thread's 8
// loads are the SAME k-chunk of 8 different rows, so:
//   - issue all 8 coalesced float4 loads (full MLP, unlike r1's serial chain),
//   - per i: 4-elem squared diff vs the thread's fixed q-chunk, then 3
//     __shfl_xor (1,2,4) to sum the 8 chunks of that row across the 8-lane
//     group; guard row < R; running min.
// No LDS tile, no barriers -> 8 blocks/CU resident (vs 4 LDS-limited in r4),
// and no loop/cross-barrier liveness -> no scratch spill (r9's failure mode:
// WRITE_SIZE 119 MB/dispatch of v[] spill traffic).
// Reducer: 1024 threads, float4 loads -> one load generation for 3907 floats.

__global__ __launch_bounds__(256) void doa_stage_kernel(
    const float* __restrict__ pp,
    const float* __restrict__ ph,
    float* __restrict__ ws,
    int R)
{
    const int t = threadIdx.x;
    const long long base_row = (long long)blockIdx.x * 256;

    // this thread's fixed 4-float chunk of the phase vector (k = t&7)
    const float4 qk = reinterpret_cast<const float4*>(ph)[t & 7];

    // 8 independent coalesced float4 loads (identical addressing to r4)
    const float4* src = reinterpret_cast<const float4*>(pp);
    const long long gmax = (long long)R * 8;
    float4 v[8];
#pragma unroll
    for (int i = 0; i < 8; ++i) {
        long long g = base_row * 8 + i * 256 + t;
        if (g >= gmax) g = 0;          // clamp; value unused for r >= R
        v[i] = src[g];
    }

    float lmin = __builtin_inff();
#pragma unroll
    for (int i = 0; i < 8; ++i) {
        const float dx = v[i].x - qk.x;
        const float dy = v[i].y - qk.y;
        const float dz = v[i].z - qk.z;
        const float dw = v[i].w - qk.w;
        float s = dx * dx + dy * dy + dz * dz + dw * dw;
        // sum the 8 chunks of this row across the 8-lane group
        s += __shfl_xor(s, 1);
        s += __shfl_xor(s, 2);
        s += __shfl_xor(s, 4);
        const long long row = base_row + i * 32 + (t >> 3);
        if (row < R) lmin = fminf(lmin, s);
    }

    // lanes within each 8-group already share lmin; fold across groups
    lmin = fminf(lmin, __shfl_xor(lmin, 8));
    lmin = fminf(lmin, __shfl_xor(lmin, 16));
    lmin = fminf(lmin, __shfl_xor(lmin, 32));

    __shared__ float wmin[4];
    if ((t & 63) == 0) wmin[t >> 6] = lmin;
    __syncthreads();
    if (t == 0) {
        // plain store: fire-and-forget, no atomic tail
        ws[blockIdx.x] = fminf(fminf(wmin[0], wmin[1]), fminf(wmin[2], wmin[3]));
    }
}

__global__ __launch_bounds__(1024) void doa_reduce_kernel(
    const float* __restrict__ ws,
    float* __restrict__ out,
    int n)
{
    const int t = threadIdx.x;
    const int n4 = n >> 2;             // float4 count (977 for n=3907)

    float s = __builtin_inff();
    // one float4 load generation covers all partials (n4 <= 1024)
    for (int i = t; i < n4; i += 1024) {
        const float4 p = reinterpret_cast<const float4*>(ws)[i];
        s = fminf(fminf(s, fminf(p.x, p.y)), fminf(p.z, p.w));
    }
    // scalar tail (n & 3 elements)
    if (t < (n & 3)) s = fminf(s, ws[(n4 << 2) + t]);

#pragma unroll
    for (int off = 1; off < 64; off <<= 1)
        s = fminf(s, __shfl_xor(s, off));

    __shared__ float wmin[16];
    if ((t & 63) == 0) wmin[t >> 6] = s;
    __syncthreads();
    if (t == 0) {
        float m = wmin[0];
#pragma unroll
        for (int w = 1; w < 16; ++w) m = fminf(m, wmin[w]);
        *out = m;
    }
}

extern "C" void kernel_launch(void* const* d_in, const int* in_sizes, int n_in,
                              void* d_out, int out_size, void* d_ws, size_t ws_size,
                              hipStream_t stream) {
    const float* pp = (const float*)d_in[0];   // possible_phases [R, 32]
    const float* ph = (const float*)d_in[1];   // phases [32]
    float* out = (float*)d_out;                // 1 fp32 scalar
    float* ws  = (float*)d_ws;                 // per-block partial mins

    const int R = in_sizes[0] / 32;
    const int grid = (R + 255) / 256;          // 3907 blocks for R = 1e6

    doa_stage_kernel<<<grid, 256, 0, stream>>>(pp, ph, ws, R);
    doa_reduce_kernel<<<1, 1024, 0, stream>>>(ws, out, grid);
}